// Round 9
// baseline (148.083 us; speedup 1.0000x reference)
//
#include <hip/hip_runtime.h>

// mean(( (model-cur)/3 - 0.0257*Lap3D(cur) - src(cur) )^2) over [8,1,128,128,128] f32.
// Zero-padded 7-point stencil.
//
// Structure (R8 baseline, heat ~31us): register z-march. Block = (x4:32, yr:8)
// slab at fixed batch, marching a z-chunk; zm/c carried in registers; per step
// only {zp, m, ym, yp} loaded (ym/yp L1-hit on the block's own planes), next
// step's loads issued distance-1 ahead and pinned with sched_barrier(0).
// R9 changes: (1) ZCHUNK 16->8 => 2048 blocks => 32 waves/CU requested (was 16)
// for latency hiding — R6/R8 showed OccupancyPercent ~25%, concurrency-limited;
// (2) finalize kernel replaced by hipMemsetAsync(d_out,0,4) + per-block float
// atomicAdd of s/N (2048 adds, error ~1e-4 << 2.9e-3 threshold).

constexpr int WW = 128;
constexpr int HH = 128;
constexpr int DD = 128;
constexpr int PLANE = HH * WW;                        // 16384 floats
constexpr long long N_ELEM = 8LL * DD * HH * WW;      // 16,777,216
constexpr int ZCHUNK = 8;
constexpr int NBLOCKS = 8 * 16 * (DD / ZCHUNK);       // batch * yslabs * zchunks = 2048

constexpr float ALPHA  = 0.0257f;
constexpr float INV_DT = 1.0f / 3.0f;
constexpr float SRC_I  = 100000.0f;
constexpr float THRESH = 1000.0f;
constexpr float INV_N  = 1.0f / (float)N_ELEM;

typedef float f32x4 __attribute__((ext_vector_type(4)));

struct L4 { float4 zp, m, ym, yp; };

__device__ __forceinline__ float4 ldg4(const float* p) {
    return *reinterpret_cast<const float4*>(p);
}
__device__ __forceinline__ float4 ldnt4(const float* p) {
    f32x4 v = __builtin_nontemporal_load(reinterpret_cast<const f32x4*>(p));
    return make_float4(v.x, v.y, v.z, v.w);
}

__device__ __forceinline__ L4 load_step(const float* __restrict__ cur,
                                        const float* __restrict__ model,
                                        int i, int ozp, int oym, int oyp) {
    L4 t;
    t.zp = ldg4(cur + i + ozp);
    t.m  = ldnt4(model + i);
    t.ym = ldg4(cur + i + oym);
    t.yp = ldg4(cur + i + oyp);
    return t;
}

__device__ __forceinline__ float sq_residual4(
        const float4 c, const float4 m,
        const float4 ym, const float4 yp,
        const float4 zm, const float4 zp,
        const float fym, const float fyp, const float fzm, const float fzp,
        const bool x_lo, const bool x_hi, float acc) {
    // x-neighbors via wave shuffle. thread = x4 + 32*yr, so lanes with x4==0 are
    // exactly {0,32} and x4==31 are {31,63}: the 32-lane-boundary leak is masked.
    float left  = __shfl_up(c.w, 1, 64);
    float right = __shfl_down(c.x, 1, 64);
    if (x_lo) left = 0.0f;
    if (x_hi) right = 0.0f;

    const float cc[4]  = {c.x, c.y, c.z, c.w};
    const float mm[4]  = {m.x, m.y, m.z, m.w};
    const float xs[6]  = {left, c.x, c.y, c.z, c.w, right};
    const float yms[4] = {ym.x, ym.y, ym.z, ym.w};
    const float yps[4] = {yp.x, yp.y, yp.z, yp.w};
    const float zms[4] = {zm.x, zm.y, zm.z, zm.w};
    const float zps[4] = {zp.x, zp.y, zp.z, zp.w};

    #pragma unroll
    for (int j = 0; j < 4; ++j) {
        float lap = xs[j] + xs[j + 2] - 6.0f * cc[j];
        lap = fmaf(fym, yms[j], lap);
        lap = fmaf(fyp, yps[j], lap);
        lap = fmaf(fzm, zms[j], lap);
        lap = fmaf(fzp, zps[j], lap);
        const float td  = (mm[j] - cc[j]) * INV_DT;
        const float src = (cc[j] > THRESH) ? SRC_I : 0.0f;
        const float r   = td - ALPHA * lap - src;
        acc = fmaf(r, r, acc);
    }
    return acc;
}

__global__ __launch_bounds__(256) void heat_loss_kernel(
        const float* __restrict__ model,
        const float* __restrict__ cur,
        float* __restrict__ out) {
    const int bx = blockIdx.x;
    const int zc = bx & 15;                // z-chunk 0..15
    const int ys = (bx >> 4) & 15;         // y-slab  0..15
    const int b  = bx >> 8;                // batch   0..7
    const int z0 = zc * ZCHUNK;

    const int x4 = threadIdx.x & 31;
    const int yr = threadIdx.x >> 5;       // 0..7
    const int y  = ys * 8 + yr;

    const bool x_lo = (x4 == 0);
    const bool x_hi = (x4 == 31);
    const float fym = (y == 0)   ? 0.0f : 1.0f;
    const float fyp = (y == 127) ? 0.0f : 1.0f;
    const int oym = (y == 0)   ? 0 : -WW;
    const int oyp = (y == 127) ? 0 :  WW;

    int i = ((b * DD + z0) * HH + y) * WW + x4 * 4;

    // prologue: zm, c planes into registers
    const int ozm0 = (z0 == 0) ? 0 : -PLANE;
    float fzm = (z0 == 0) ? 0.0f : 1.0f;
    float4 zm = ldg4(cur + i + ozm0);
    float4 c  = ldg4(cur + i);

    // step-0 loads (zp, m, ym, yp); last chunk's final step clamps zp
    L4 t0 = load_step(cur, model, i, PLANE, oym, oyp);

    float acc = 0.0f;

    #pragma unroll 1
    for (int s = 0; s < ZCHUNK - 1; ++s) {
        const int zz1 = z0 + s + 1;                      // next step's z
        const int ozp1 = (zz1 == 127) ? 0 : PLANE;
        // issue next step's 4 loads
        L4 t1 = load_step(cur, model, i + PLANE, ozp1, oym, oyp);

        // pin: loads above may not sink below; compute may not hoist above.
        __builtin_amdgcn_sched_barrier(0);

        acc = sq_residual4(c, t0.m, t0.ym, t0.yp, zm, t0.zp,
                           fym, fyp, fzm, 1.0f, x_lo, x_hi, acc);
        zm = c;
        c  = t0.zp;
        fzm = 1.0f;
        t0 = t1;
        i += PLANE;
    }

    // final step of the chunk; zp weight 0 iff z==127
    const float fzp_last = (z0 + ZCHUNK - 1 == 127) ? 0.0f : 1.0f;
    acc = sq_residual4(c, t0.m, t0.ym, t0.yp, zm, t0.zp,
                       fym, fyp, fzm, fzp_last, x_lo, x_hi, acc);

    // 64-lane wave reduction
    #pragma unroll
    for (int off = 32; off > 0; off >>= 1)
        acc += __shfl_down(acc, off, 64);

    __shared__ float wsum[4];
    const int lane = threadIdx.x & 63;
    const int wave = threadIdx.x >> 6;
    if (lane == 0) wsum[wave] = acc;
    __syncthreads();

    if (threadIdx.x == 0) {
        const float s = (wsum[0] + wsum[1] + wsum[2] + wsum[3]) * INV_N;
        atomicAdd(out, s);   // 2048 float adds into ~0.7: err ~1e-4 << 2.9e-3 thr
    }
}

extern "C" void kernel_launch(void* const* d_in, const int* in_sizes, int n_in,
                              void* d_out, int out_size, void* d_ws, size_t ws_size,
                              hipStream_t stream) {
    const float* model = (const float*)d_in[0];   // model_output
    const float* cur   = (const float*)d_in[1];   // current_input
    float* out = (float*)d_out;

    hipMemsetAsync(out, 0, sizeof(float), stream);   // graph-capturable memset node
    heat_loss_kernel<<<NBLOCKS, 256, 0, stream>>>(model, cur, out);
}

// Round 11
// 131.279 us; speedup vs baseline: 1.1280x; 1.1280x over previous
//
#include <hip/hip_runtime.h>

// mean(( (model-cur)/3 - 0.0257*Lap3D(cur) - src(cur) )^2) over [8,1,128,128,128] f32.
// Zero-padded 7-point stencil.
//
// R8 baseline (best, heat ~33us): register z-march, block=(x4:32,yr:8) slab,
// ZCHUNK=16, distance-1 prefetch pinned by sched_barrier. R6/R8 evidence: time
// scales with global float4 loads per step (vmem-path-bound, not HBM/VALU/occ).
// R10 single change: ym/yp come from a double-buffered 10-row LDS plane slab
// (own 8 rows written from the z-march register + 2 halo rows loaded by the
// first 64 threads). Global wave-loads per block-step: 16 -> 9.
// R9 lesson (reverted): ZCHUNK=8 + single-address atomic finalize regressed.

constexpr int WW = 128;
constexpr int HH = 128;
constexpr int DD = 128;
constexpr int PLANE = HH * WW;                        // 16384 floats
constexpr long long N_ELEM = 8LL * DD * HH * WW;      // 16,777,216
constexpr int ZCHUNK = 16;
constexpr int NBLOCKS = 8 * 16 * (DD / ZCHUNK);       // 1024

constexpr float ALPHA  = 0.0257f;
constexpr float INV_DT = 1.0f / 3.0f;
constexpr float SRC_I  = 100000.0f;
constexpr float THRESH = 1000.0f;

typedef float f32x4 __attribute__((ext_vector_type(4)));

__device__ __forceinline__ float4 ldg4(const float* p) {
    return *reinterpret_cast<const float4*>(p);
}
__device__ __forceinline__ float4 ldnt4(const float* p) {
    f32x4 v = __builtin_nontemporal_load(reinterpret_cast<const f32x4*>(p));
    return make_float4(v.x, v.y, v.z, v.w);
}

__device__ __forceinline__ float sq_residual4(
        const float4 c, const float4 m,
        const float4 ym, const float4 yp,
        const float4 zm, const float4 zp,
        const float fym, const float fyp, const float fzm, const float fzp,
        const bool x_lo, const bool x_hi, float acc) {
    // x-neighbors via wave shuffle. thread = x4 + 32*yr: lanes with x4==0 are
    // exactly {0,32}, x4==31 are {31,63}, so the 32-lane-boundary leak is masked.
    float left  = __shfl_up(c.w, 1, 64);
    float right = __shfl_down(c.x, 1, 64);
    if (x_lo) left = 0.0f;
    if (x_hi) right = 0.0f;

    const float cc[4]  = {c.x, c.y, c.z, c.w};
    const float mm[4]  = {m.x, m.y, m.z, m.w};
    const float xs[6]  = {left, c.x, c.y, c.z, c.w, right};
    const float yms[4] = {ym.x, ym.y, ym.z, ym.w};
    const float yps[4] = {yp.x, yp.y, yp.z, yp.w};
    const float zms[4] = {zm.x, zm.y, zm.z, zm.w};
    const float zps[4] = {zp.x, zp.y, zp.z, zp.w};

    #pragma unroll
    for (int j = 0; j < 4; ++j) {
        float lap = xs[j] + xs[j + 2] - 6.0f * cc[j];
        lap = fmaf(fym, yms[j], lap);
        lap = fmaf(fyp, yps[j], lap);
        lap = fmaf(fzm, zms[j], lap);
        lap = fmaf(fzp, zps[j], lap);
        const float td  = (mm[j] - cc[j]) * INV_DT;
        const float src = (cc[j] > THRESH) ? SRC_I : 0.0f;
        const float r   = td - ALPHA * lap - src;
        acc = fmaf(r, r, acc);
    }
    return acc;
}

__global__ __launch_bounds__(256) void heat_loss_kernel(
        const float* __restrict__ model,
        const float* __restrict__ cur,
        float* __restrict__ block_sums) {
    const int bx = blockIdx.x;
    const int zc = bx & 7;                 // z-chunk 0..7
    const int ys = (bx >> 3) & 15;         // y-slab  0..15
    const int b  = bx >> 7;                // batch   0..7
    const int z0 = zc * ZCHUNK;

    const int tid = threadIdx.x;
    const int x4 = tid & 31;
    const int yr = tid >> 5;               // 0..7
    const int y  = ys * 8 + yr;

    const bool x_lo = (x4 == 0);
    const bool x_hi = (x4 == 31);
    const float fym = (y == 0)   ? 0.0f : 1.0f;
    const float fyp = (y == 127) ? 0.0f : 1.0f;

    // LDS plane slab, double-buffered: rows 0..9 = global rows y0-1 .. y0+8.
    __shared__ __align__(16) float lds[2][10][128];

    int i = ((b * DD + z0) * HH + y) * WW + x4 * 4;

    // halo-row duty: threads 0..31 load row y0-1, threads 32..63 row y0+8
    // (clamped; consumers mask via fym/fyp so clamped garbage never counts).
    const bool has_edge = (tid < 64);
    int ei = 0;
    int erow_lds = 0;
    if (has_edge) {
        int ey = (tid < 32) ? (ys * 8 - 1) : (ys * 8 + 8);
        ey = min(127, max(0, ey));
        erow_lds = (tid < 32) ? 0 : 9;
        ei = ((b * DD + z0) * HH + ey) * WW + (tid & 31) * 4;
    }

    // prologue: registers zm (plane z0-1, masked) and c (plane z0)
    float fzm = (z0 == 0) ? 0.0f : 1.0f;
    float4 zm = ldg4(cur + i + ((z0 == 0) ? 0 : -PLANE));
    float4 c  = ldg4(cur + i);
    // step-0 prefetch: zp = plane z0+1 (z0<=112 so always valid), m = plane z0
    float4 zp0 = ldg4(cur + i + PLANE);
    float4 m0  = ldnt4(model + i);
    float4 e0;
    if (has_edge) e0 = ldg4(cur + ei);

    // populate plane-z0 slab
    *reinterpret_cast<float4*>(&lds[0][yr + 1][x4 * 4]) = c;
    if (has_edge) *reinterpret_cast<float4*>(&lds[0][erow_lds][(tid & 31) * 4]) = e0;
    __syncthreads();

    float acc = 0.0f;
    int cb = 0;

    #pragma unroll 1
    for (int s = 0; s < ZCHUNK - 1; ++s) {
        // prefetch for step s+1: zp = plane s+2 (clamped at 127), m/halo = plane s+1
        const int ozp = (z0 + s + 2 > 127) ? 0 : PLANE;
        float4 zp1 = ldg4(cur + i + PLANE + ozp);
        float4 m1  = ldnt4(model + i + PLANE);
        float4 e1;
        if (has_edge) e1 = ldg4(cur + ei + PLANE);

        // pin: prefetch may not sink below; compute may not hoist above.
        __builtin_amdgcn_sched_barrier(0);

        // ym/yp of plane s from the staged slab
        const float4 ym = *reinterpret_cast<const float4*>(&lds[cb][yr][x4 * 4]);
        const float4 yp = *reinterpret_cast<const float4*>(&lds[cb][yr + 2][x4 * 4]);

        acc = sq_residual4(c, m0, ym, yp, zm, zp0,
                           fym, fyp, fzm, 1.0f, x_lo, x_hi, acc);

        // rotate registers; write plane s+1 slab into the other buffer
        zm = c; c = zp0; fzm = 1.0f;
        zp0 = zp1; m0 = m1;
        *reinterpret_cast<float4*>(&lds[cb ^ 1][yr + 1][x4 * 4]) = c;
        if (has_edge) *reinterpret_cast<float4*>(&lds[cb ^ 1][erow_lds][(tid & 31) * 4]) = e1;
        cb ^= 1;
        i += PLANE;
        ei += PLANE;
        __syncthreads();
    }

    // final step: plane z0+15; zp masked iff it is z==127
    {
        const float4 ym = *reinterpret_cast<const float4*>(&lds[cb][yr][x4 * 4]);
        const float4 yp = *reinterpret_cast<const float4*>(&lds[cb][yr + 2][x4 * 4]);
        const float fzp_last = (z0 + ZCHUNK - 1 == 127) ? 0.0f : 1.0f;
        acc = sq_residual4(c, m0, ym, yp, zm, zp0,
                           fym, fyp, fzm, fzp_last, x_lo, x_hi, acc);
    }

    // 64-lane wave reduction
    #pragma unroll
    for (int off = 32; off > 0; off >>= 1)
        acc += __shfl_down(acc, off, 64);

    __shared__ float wsum[4];
    const int lane = tid & 63;
    const int wave = tid >> 6;
    if (lane == 0) wsum[wave] = acc;
    __syncthreads();

    if (tid == 0)
        block_sums[blockIdx.x] = wsum[0] + wsum[1] + wsum[2] + wsum[3];
}

__global__ __launch_bounds__(256) void finalize_kernel(
        const float* __restrict__ block_sums, float* __restrict__ out) {
    double a = 0.0;
    for (int j = threadIdx.x; j < NBLOCKS; j += 256)
        a += (double)block_sums[j];

    #pragma unroll
    for (int off = 32; off > 0; off >>= 1)
        a += __shfl_down(a, off, 64);

    __shared__ double wsum[4];
    const int lane = threadIdx.x & 63;
    const int wave = threadIdx.x >> 6;
    if (lane == 0) wsum[wave] = a;
    __syncthreads();

    if (threadIdx.x == 0)
        out[0] = (float)((wsum[0] + wsum[1] + wsum[2] + wsum[3]) / (double)N_ELEM);
}

extern "C" void kernel_launch(void* const* d_in, const int* in_sizes, int n_in,
                              void* d_out, int out_size, void* d_ws, size_t ws_size,
                              hipStream_t stream) {
    const float* model = (const float*)d_in[0];   // model_output
    const float* cur   = (const float*)d_in[1];   // current_input
    float* block_sums = (float*)d_ws;             // NBLOCKS floats, fully written each call
    float* out = (float*)d_out;

    heat_loss_kernel<<<NBLOCKS, 256, 0, stream>>>(model, cur, block_sums);
    finalize_kernel<<<1, 256, 0, stream>>>(block_sums, out);
}